// Round 4
// baseline (433.576 us; speedup 1.0000x reference)
//
#include <hip/hip_runtime.h>
#include <hip/hip_fp16.h>
#include <math.h>

#define NB 16
#define PI2 6.28318530717958647692f

struct Levels {
  int n[6], kn[6];
  int zt_off[6];   // float elements
  int zxy_off[6];  // float elements
  int z6_off[6];   // half elements
  int u_off[6];    // half elements
  int gstart[7];
  float scale[6];
};
struct WArgs {
  const float* w[12];
};

// ---------------- small load/store helpers ----------------
__device__ inline float4 ld4g(const float* p) { return *reinterpret_cast<const float4*>(p); }
__device__ inline float4 ld4g(const __half* p) {
  float2 raw = *reinterpret_cast<const float2*>(p);
  union { float2 f; __half2 h[2]; } u;
  u.f = raw;
  float2 a = __half22float2(u.h[0]), b = __half22float2(u.h[1]);
  return make_float4(a.x, a.y, b.x, b.y);
}
__device__ inline void st4h(__half* p, float a, float b, float c, float d) {
  union { __half2 h[2]; float2 f; } u;
  u.h[0] = __floats2half2_rn(a, b);
  u.h[1] = __floats2half2_rn(c, d);
  *reinterpret_cast<float2*>(p) = u.f;
}

// ---------------- twiddle tables ----------------
__global__ __launch_bounds__(256) void k_init(float* __restrict__ twt, float* __restrict__ twx) {
  int tid = threadIdx.x;
  for (int i = tid; i < 5 * 64; i += 256) {
    int k = i >> 6, t = i & 63;
    float ang = (float)((k * t) & 63) * (PI2 / 64.f);
    float s, c;
    sincosf(ang, &s, &c);
    twt[2 * i] = c;
    twt[2 * i + 1] = s;
  }
  for (int lev = 0; lev < 6; ++lev) {
    int n = 32 >> lev;
    int kn = n < 10 ? n : 10;
    float* tx = twx + lev * 640;
    for (int i = tid; i < kn * n; i += 256) {
      int j = i / n, m = i % n;
      int k = (kn < 10) ? j : (j < 5 ? j : n - 10 + j);
      float ang = (float)((k * m) % n) * (PI2 / (float)n);
      float s, c;
      sincosf(ang, &s, &c);
      tx[2 * i] = c;
      tx[2 * i + 1] = s;
    }
  }
}

// ---------------- per-(ds) register t-DFT + 16-lane butterfly + store ----------------
__device__ inline void dft_reduce_store(const float (&a)[9][4], const float (&tc)[5][4],
                                        const float (&tsn)[5][4], float* __restrict__ out,
                                        int tq, bool active, long rowbase, long nn,
                                        float scale) {
#pragma unroll
  for (int ch = 0; ch < 9; ++ch) {
#pragma unroll
    for (int k = 0; k < 5; ++k) {
      float re = a[ch][0] * tc[k][0] + a[ch][1] * tc[k][1] + a[ch][2] * tc[k][2] +
                 a[ch][3] * tc[k][3];
      float im = -(a[ch][0] * tsn[k][0] + a[ch][1] * tsn[k][1] + a[ch][2] * tsn[k][2] +
                   a[ch][3] * tsn[k][3]);
#pragma unroll
      for (int m = 1; m < 16; m <<= 1) {
        re += __shfl_xor(re, m, 16);
        im += __shfl_xor(im, m, 16);
      }
      if (active) {
        int idx = ch * 10 + 2 * k;
        long addr = (rowbase + (long)ch * nn) * 10 + 2 * k;
        if ((idx & 15) == tq) out[addr] = re * scale;
        if (((idx + 1) & 15) == tq) out[addr + 1] = im * scale;
      }
    }
  }
}

// ---------------- fused wavelet analysis + forward t-DFT (register version) -----------
// thread = (pos, t-quad). float4 x loads, zero LDS data staging.
template <typename T>
__global__ __launch_bounds__(256) void k_wavdft(const T* __restrict__ xin,
                                                const float* __restrict__ ecd,
                                                const float* __restrict__ ecs,
                                                __half* __restrict__ sout,
                                                float* __restrict__ Zd, float* __restrict__ Zs,
                                                const float* __restrict__ twt, int n,
                                                float scale) {
  __shared__ float tw[640];
  int tid = threadIdx.x;
  for (int i = tid; i < 640; i += 256) tw[i] = twt[i];
  int p = tid >> 4, tq = tid & 15;
  long pos = (long)blockIdx.x * 16 + p;
  long total = (long)NB * n * n;
  bool active = pos < total;
  float acc0[9][4], acc1[9][4];
#pragma unroll
  for (int o = 0; o < 9; ++o)
#pragma unroll
    for (int j = 0; j < 4; ++j) { acc0[o][j] = 0.f; acc1[o][j] = 0.f; }
  int b = 0, rem = 0;
  if (active) {
    b = (int)(pos / (n * n));
    rem = (int)(pos % (n * n));
    int xp = rem / n, yp = rem % n;
    int n2 = 2 * n;
    const T* xb = xin + (long)b * 9 * n2 * n2 * 64;
#pragma unroll
    for (int q = 0; q < 4; ++q) {
      int X = 2 * xp + (q >> 1), Y = 2 * yp + (q & 1);
#pragma unroll
      for (int i = 0; i < 9; ++i) {
        float4 v = ld4g(xb + (((long)i * n2 + X) * n2 + Y) * 64 + tq * 4);
        const float* wd = &ecd[(q * 9 + i) * 9];
        const float* wsv = &ecs[(q * 9 + i) * 9];
#pragma unroll
        for (int o = 0; o < 9; ++o) {
          float cd = wd[o], cw = wsv[o];
          acc0[o][0] += v.x * cd; acc0[o][1] += v.y * cd;
          acc0[o][2] += v.z * cd; acc0[o][3] += v.w * cd;
          acc1[o][0] += v.x * cw; acc1[o][1] += v.y * cw;
          acc1[o][2] += v.z * cw; acc1[o][3] += v.w * cw;
        }
      }
    }
    long cs64 = (long)n * n * 64;
#pragma unroll
    for (int o = 0; o < 9; ++o)
      st4h(sout + ((long)b * 9 + o) * cs64 + (long)rem * 64 + tq * 4, acc1[o][0], acc1[o][1],
           acc1[o][2], acc1[o][3]);
  }
  __syncthreads();
  float tc[5][4], tsn[5][4];
#pragma unroll
  for (int k = 0; k < 5; ++k)
#pragma unroll
    for (int j = 0; j < 4; ++j) {
      float2 cs2 = *reinterpret_cast<const float2*>(&tw[2 * (k * 64 + tq * 4 + j)]);
      tc[k][j] = cs2.x;
      tsn[k][j] = cs2.y;
    }
  long nn = (long)n * n;
  long rowbase = (long)b * 9 * nn + rem;
  dft_reduce_store(acc0, tc, tsn, Zd, tq, active, rowbase, nn, scale);
  dft_reduce_store(acc1, tc, tsn, Zs, tq, active, rowbase, nn, scale);
}

// ---------------- all-level forward y-DFT then x-DFT ----------------
__global__ __launch_bounds__(256) void k_bc_all(const float* __restrict__ Zt_d,
                                                const float* __restrict__ Zt_s,
                                                float* __restrict__ Zxy_d,
                                                float* __restrict__ Zxy_s,
                                                const float* __restrict__ twx_all, Levels lv) {
  __shared__ float S1[3200];
  __shared__ float tx[640];
  int lev = blockIdx.x / 288;
  int r = blockIdx.x % 288;
  int ds = r / 144, bc = r % 144;
  int n = lv.n[lev], kn = lv.kn[lev];
  int tid = threadIdx.x;
  const float* twx = twx_all + lev * 640;
  for (int i = tid; i < kn * n * 2; i += 256) tx[i] = twx[i];
  __syncthreads();
  const float* in = (ds ? Zt_s : Zt_d) + lv.zt_off[lev] + (long)bc * n * n * 10;
  float* out = (ds ? Zxy_s : Zxy_d) + lv.zxy_off[lev] + (long)bc * kn * kn * 10;
  int s1n = n * kn * 5;
  for (int idx = tid; idx < s1n; idx += 256) {
    int kz = idx % 5, jy = (idx / 5) % kn, x = idx / (5 * kn);
    float sr = 0.f, si = 0.f;
    const float2* row2 = reinterpret_cast<const float2*>(in + (long)x * n * 10);
    for (int y = 0; y < n; ++y) {
      float2 z = row2[y * 5 + kz];
      float2 cs2 = *reinterpret_cast<const float2*>(&tx[2 * (jy * n + y)]);
      sr += z.x * cs2.x + z.y * cs2.y;
      si += z.y * cs2.x - z.x * cs2.y;
    }
    *reinterpret_cast<float2*>(&S1[2 * idx]) = make_float2(sr, si);
  }
  __syncthreads();
  int s2n = kn * kn * 5;
  for (int idx = tid; idx < s2n; idx += 256) {
    int kz = idx % 5, jy = (idx / 5) % kn, jx = idx / (5 * kn);
    float sr = 0.f, si = 0.f;
    for (int x = 0; x < n; ++x) {
      float2 z = *reinterpret_cast<const float2*>(&S1[2 * ((x * kn + jy) * 5 + kz)]);
      float2 cs2 = *reinterpret_cast<const float2*>(&tx[2 * (jx * n + x)]);
      sr += z.x * cs2.x + z.y * cs2.y;
      si += z.y * cs2.x - z.x * cs2.y;
    }
    *reinterpret_cast<float2*>(&out[2 * idx]) = make_float2(sr, si);
  }
}

// ---------------- all-level fused mode-mix + inverse expand x,y ----------------
__global__ __launch_bounds__(256) void k_efmix_all(const float* __restrict__ Zxy_d,
                                                   const float* __restrict__ Zxy_s,
                                                   __half* __restrict__ Z6a,
                                                   __half* __restrict__ Z6b,
                                                   __half* __restrict__ Z6c, WArgs wa,
                                                   const float* __restrict__ twx_all,
                                                   Levels lv) {
  __shared__ float zin[9000];
  __shared__ float zm[1000];
  __shared__ float S1[3200];
  __shared__ float tx[640];
  int lev = blockIdx.x / 432;
  int r = blockIdx.x % 432;
  int batch = r / 144;
  int rr = r % 144;
  int b = rr / 9, o = rr % 9;
  int n = lv.n[lev], kn = lv.kn[lev];
  int nm = kn * kn * 5;
  int tid = threadIdx.x;
  const float* twx = twx_all + lev * 640;
  const float* in = (batch == 1 ? Zxy_s : Zxy_d) + lv.zxy_off[lev] + (long)b * 9 * nm * 2;
  __half* out = (batch == 0 ? Z6a : batch == 1 ? Z6b : Z6c) + lv.z6_off[lev] +
                ((long)(b * 9 + o)) * n * n * 10;
  for (int i = tid; i < kn * n * 2; i += 256) tx[i] = twx[i];
  for (int i = tid; i < 9 * nm; i += 256)
    reinterpret_cast<float2*>(zin)[i] = reinterpret_cast<const float2*>(in)[i];
  __syncthreads();
  int l1 = (5 < n / 2 + 1) ? 5 : n / 2 + 1;
  for (int m = tid; m < nm; m += 256) {
    int kz = m % 5, jy = (m / 5) % kn, jx = m / (5 * kn);
    int kx = (kn < 10) ? jx : (jx < 5 ? jx : n - 10 + jx);
    int ky = (kn < 10) ? jy : (jy < 5 ? jy : n - 10 + jy);
    bool lx = kx < l1, hx = kx >= n - l1, ly = ky < l1, hy = ky >= n - l1;
    const float* wsel;
    int wx, wy;
    if (hx && hy) { wsel = wa.w[batch * 4 + 3]; wx = kx - (n - l1); wy = ky - (n - l1); }
    else if (lx && hy) { wsel = wa.w[batch * 4 + 2]; wx = kx; wy = ky - (n - l1); }
    else if (hx && ly) { wsel = wa.w[batch * 4 + 1]; wx = kx - (n - l1); wy = ky; }
    else { wsel = wa.w[batch * 4 + 0]; wx = kx; wy = ky; }
    const float* wp = wsel + o * 250 + wx * 50 + wy * 10 + kz * 2;
    float sr = 0.f, si = 0.f;
#pragma unroll
    for (int i = 0; i < 9; ++i) {
      float2 z = *reinterpret_cast<const float2*>(&zin[(i * nm + m) * 2]);
      float2 w2 = *reinterpret_cast<const float2*>(&wp[i * 2250]);
      sr += z.x * w2.x - z.y * w2.y;
      si += z.x * w2.y + z.y * w2.x;
    }
    *reinterpret_cast<float2*>(&zm[2 * m]) = make_float2(sr, si);
  }
  __syncthreads();
  int s1n = n * kn * 5;
  for (int idx = tid; idx < s1n; idx += 256) {
    int kz = idx % 5, jy = (idx / 5) % kn, x = idx / (5 * kn);
    float sr = 0.f, si = 0.f;
    for (int jx = 0; jx < kn; ++jx) {
      float2 z = *reinterpret_cast<const float2*>(&zm[2 * ((jx * kn + jy) * 5 + kz)]);
      float2 cs2 = *reinterpret_cast<const float2*>(&tx[2 * (jx * n + x)]);
      sr += z.x * cs2.x - z.y * cs2.y;
      si += z.x * cs2.y + z.y * cs2.x;
    }
    *reinterpret_cast<float2*>(&S1[2 * idx]) = make_float2(sr, si);
  }
  __syncthreads();
  int s2n = n * n * 5;
  for (int idx = tid; idx < s2n; idx += 256) {
    int kz = idx % 5, y = (idx / 5) % n, x = idx / (5 * n);
    float sr = 0.f, si = 0.f;
    for (int jy = 0; jy < kn; ++jy) {
      float2 z = *reinterpret_cast<const float2*>(&S1[2 * ((x * kn + jy) * 5 + kz)]);
      float2 cs2 = *reinterpret_cast<const float2*>(&tx[2 * (jy * n + y)]);
      sr += z.x * cs2.x - z.y * cs2.y;
      si += z.x * cs2.y + z.y * cs2.x;
    }
    *reinterpret_cast<__half2*>(out + 2 * idx) = __floats2half2_rn(sr, si);
  }
}

// ---------------- all-level inverse-t(c2r) + ReLU + lo conv ----------------
__global__ __launch_bounds__(256) void k_gh3_all(const __half* __restrict__ Z6a,
                                                 const __half* __restrict__ Z6b,
                                                 const __half* __restrict__ Z6c,
                                                 const float* __restrict__ a_low,
                                                 const float* __restrict__ a_lob,
                                                 const float* __restrict__ b_low,
                                                 const float* __restrict__ b_lob,
                                                 const float* __restrict__ c_low,
                                                 const float* __restrict__ c_lob,
                                                 __half* __restrict__ Ud,
                                                 __half* __restrict__ Us,
                                                 const float* __restrict__ twt, Levels lv) {
  __shared__ float tw[640];
  __shared__ float zz[3][4][90];
  int tid = threadIdx.x;
  for (int i = tid; i < 640; i += 256) tw[i] = twt[i];
  int lev = 0;
  while (lev < 5 && (int)blockIdx.x >= lv.gstart[lev + 1]) ++lev;
  int n = lv.n[lev];
  float scale = lv.scale[lev];
  long pos0 = (long)(blockIdx.x - lv.gstart[lev]) * 4;
  long total = (long)NB * n * n;
  const __half* zbuf[3] = {Z6a + lv.z6_off[lev], Z6b + lv.z6_off[lev], Z6c + lv.z6_off[lev]};
  // staging: 540 half2 loads
  for (int i = tid; i < 540; i += 256) {
    int bi = i / 180;
    int rr2 = i % 180;
    int p = rr2 / 45;
    int q = rr2 % 45;
    int ch = q / 5, kz = q % 5;
    long pos = pos0 + p;
    if (pos < total) {
      int b = (int)(pos / (n * n));
      int rem = (int)(pos % (n * n));
      const __half2* src = reinterpret_cast<const __half2*>(
          zbuf[bi] + ((long)(b * 9 + ch) * n * n + rem) * 10 + 2 * kz);
      float2 f = __half22float2(*src);
      *reinterpret_cast<float2*>(&zz[bi][p][ch * 10 + 2 * kz]) = f;
    }
  }
  __syncthreads();
  int p = tid / 64, t = tid & 63;
  long pos = pos0 + p;
  if (pos >= total) return;
  int b = (int)(pos / (n * n));
  int rem = (int)(pos % (n * n));
  float tc[4], tsn[4];
#pragma unroll
  for (int k = 1; k < 5; ++k) {
    float2 cs2 = *reinterpret_cast<const float2*>(&tw[2 * (k * 64 + t)]);
    tc[k - 1] = cs2.x;
    tsn[k - 1] = cs2.y;
  }
  float rva[9], rvb[9], rvc[9];
#pragma unroll
  for (int i = 0; i < 9; ++i) {
    const float* za = &zz[0][p][i * 10];
    const float* zb = &zz[1][p][i * 10];
    const float* zc = &zz[2][p][i * 10];
    float va = za[0], vb = zb[0], vc = zc[0];
#pragma unroll
    for (int k = 1; k < 5; ++k) {
      float2 za2 = *reinterpret_cast<const float2*>(&za[2 * k]);
      float2 zb2 = *reinterpret_cast<const float2*>(&zb[2 * k]);
      float2 zc2 = *reinterpret_cast<const float2*>(&zc[2 * k]);
      va += 2.f * (za2.x * tc[k - 1] - za2.y * tsn[k - 1]);
      vb += 2.f * (zb2.x * tc[k - 1] - zb2.y * tsn[k - 1]);
      vc += 2.f * (zc2.x * tc[k - 1] - zc2.y * tsn[k - 1]);
    }
    rva[i] = fmaxf(va * scale, 0.f);
    rvb[i] = fmaxf(vb * scale, 0.f);
    rvc[i] = fmaxf(vc * scale, 0.f);
  }
  long cs = (long)n * n * 64;
  long ob = (long)b * 9 * cs + (long)rem * 64 + t;
  __half* ud = Ud + lv.u_off[lev];
  __half* us = Us + lv.u_off[lev];
#pragma unroll
  for (int o = 0; o < 9; ++o) {
    float du = a_lob[o] + b_lob[o];
    float usv = c_lob[o];
#pragma unroll
    for (int i = 0; i < 9; ++i) {
      du += a_low[o * 9 + i] * rva[i] + b_low[o * 9 + i] * rvb[i];
      usv += c_low[o * 9 + i] * rvc[i];
    }
    ud[ob + o * cs] = __float2half(du);
    us[ob + o * cs] = __float2half(usv);
  }
}

// ---------------- single-pos recon step helper ----------------
__device__ inline void step1pos(const float* __restrict__ in, float* __restrict__ outp,
                                const __half* __restrict__ us, const __half* __restrict__ ud,
                                long chs, const float* __restrict__ rc, int t) {
  float cat[18];
#pragma unroll
  for (int i = 0; i < 9; ++i) cat[i] = in[i * 64 + t] + __half2float(us[chs * i + t]);
#pragma unroll
  for (int i = 0; i < 9; ++i) cat[9 + i] = __half2float(ud[chs * i + t]);
#pragma unroll
  for (int o = 0; o < 9; ++o) {
    float s = 0.f;
#pragma unroll
    for (int i = 0; i < 18; ++i) s += cat[i] * rc[i * 9 + o];
    outp[o * 64 + t] = s;
  }
}

// ---------------- fully fused reconstruction: t0 + all 6 levels ----------------
// block = (b, 8x8 tile of final 64x64). LDS-staged chain, fp32.
__global__ __launch_bounds__(256) void k_recon_fused(
    const __half* __restrict__ s5, const float* __restrict__ t0w,
    const float* __restrict__ t0b, const __half* __restrict__ Ud,
    const __half* __restrict__ Us, const float* __restrict__ rcee,
    const float* __restrict__ rceo, const float* __restrict__ roe_,
    const float* __restrict__ roo_, float* __restrict__ out, Levels lv) {
  __shared__ float A[576];
  __shared__ float Bq[576];
  __shared__ float mid[4 * 580];
  __shared__ float big[16 * 580];
  int tid = threadIdx.x;
  int b = blockIdx.x >> 6;
  int T = blockIdx.x & 63;
  int tx = T >> 3, ty = T & 7;
  const float* rcw[4] = {rcee, rceo, roe_, roo_};

  // t0
  if (tid < 64) {
    int t = tid;
    float v[9];
#pragma unroll
    for (int i = 0; i < 9; ++i) v[i] = __half2float(s5[((long)b * 9 + i) * 64 + t]);
#pragma unroll
    for (int o = 0; o < 9; ++o) {
      float s = t0b[o];
#pragma unroll
      for (int i = 0; i < 9; ++i) s += t0w[o * 9 + i] * v[i];
      A[o * 64 + t] = s;
    }
  }
  __syncthreads();
  // steps 5,4,3 (single ancestor pos each)
  if (tid < 64) {
    int t = tid;
    {  // step 5: m=1, inpos 0; parity from (tx>>2,ty>>2)
      int sel = ((tx >> 2) & 1) * 2 + ((ty >> 2) & 1);
      long base = lv.u_off[5] + (long)b * 9 * 64;
      step1pos(A, Bq, Us + base, Ud + base, 64, rcw[sel], t);
    }
  }
  __syncthreads();
  if (tid < 64) {
    int t = tid;
    {  // step 4: m=2, inpos (tx>>2, ty>>2); parity (tx>>1, ty>>1)
      int ip = (tx >> 2) * 2 + (ty >> 2);
      int sel = ((tx >> 1) & 1) * 2 + ((ty >> 1) & 1);
      long base = lv.u_off[4] + ((long)b * 9 * 4 + ip) * 64;
      step1pos(Bq, A, Us + base, Ud + base, 4 * 64, rcw[sel], t);
    }
  }
  __syncthreads();
  if (tid < 64) {
    int t = tid;
    {  // step 3: m=4, inpos (tx>>1, ty>>1); parity (tx, ty)
      int ip = (tx >> 1) * 4 + (ty >> 1);
      int sel = (tx & 1) * 2 + (ty & 1);
      long base = lv.u_off[3] + ((long)b * 9 * 16 + ip) * 64;
      step1pos(A, Bq, Us + base, Ud + base, 16 * 64, rcw[sel], t);
    }
  }
  __syncthreads();
  {  // step 2: m=8, in Bq (G3 pos (tx,ty)) -> mid 2x2
    int q = tid >> 6, t = tid & 63;
    int ip = tx * 8 + ty;
    long base = lv.u_off[2] + ((long)b * 9 * 64 + ip) * 64;
    step1pos(Bq, &mid[q * 580], Us + base, Ud + base, 64 * 64, rcw[q], t);
  }
  __syncthreads();
  {  // step 1: m=16, in mid -> big 4x4 (float4 over t)
    int pos16 = tid >> 4, tq = tid & 15;
    int ox = pos16 >> 2, oy = pos16 & 3;
    int q = (ox >> 1) * 2 + (oy >> 1);
    int gx = 2 * tx + (ox >> 1), gy = 2 * ty + (oy >> 1);
    int ip = gx * 16 + gy;
    long base = lv.u_off[1] + ((long)b * 9 * 256 + ip) * 64 + tq * 4;
    const float* rc = rcw[(ox & 1) * 2 + (oy & 1)];
    float cat[18][4];
#pragma unroll
    for (int i = 0; i < 9; ++i) {
      float4 m4 = *reinterpret_cast<const float4*>(&mid[q * 580 + i * 64 + tq * 4]);
      float4 u4 = ld4g(Us + base + (long)i * 256 * 64);
      cat[i][0] = m4.x + u4.x; cat[i][1] = m4.y + u4.y;
      cat[i][2] = m4.z + u4.z; cat[i][3] = m4.w + u4.w;
      float4 d4 = ld4g(Ud + base + (long)i * 256 * 64);
      cat[9 + i][0] = d4.x; cat[9 + i][1] = d4.y; cat[9 + i][2] = d4.z; cat[9 + i][3] = d4.w;
    }
#pragma unroll
    for (int o = 0; o < 9; ++o) {
      float s0 = 0.f, s1 = 0.f, s2 = 0.f, s3 = 0.f;
#pragma unroll
      for (int i = 0; i < 18; ++i) {
        float w = rc[i * 9 + o];
        s0 += cat[i][0] * w; s1 += cat[i][1] * w; s2 += cat[i][2] * w; s3 += cat[i][3] * w;
      }
      *reinterpret_cast<float4*>(&big[pos16 * 580 + o * 64 + tq * 4]) =
          make_float4(s0, s1, s2, s3);
    }
  }
  __syncthreads();
  {  // step 0: m=32, in big -> global out (4 children per input pos)
    int q16 = tid >> 4, tq = tid & 15;
    int ix = q16 >> 2, iy = q16 & 3;
    int gx = 4 * tx + ix, gy = 4 * ty + iy;
    int ip = gx * 32 + gy;
    long base = lv.u_off[0] + ((long)b * 9 * 1024 + ip) * 64 + tq * 4;
    float cat[18][4];
#pragma unroll
    for (int i = 0; i < 9; ++i) {
      float4 m4 = *reinterpret_cast<const float4*>(&big[q16 * 580 + i * 64 + tq * 4]);
      float4 u4 = ld4g(Us + base + (long)i * 1024 * 64);
      cat[i][0] = m4.x + u4.x; cat[i][1] = m4.y + u4.y;
      cat[i][2] = m4.z + u4.z; cat[i][3] = m4.w + u4.w;
      float4 d4 = ld4g(Ud + base + (long)i * 1024 * 64);
      cat[9 + i][0] = d4.x; cat[9 + i][1] = d4.y; cat[9 + i][2] = d4.z; cat[9 + i][3] = d4.w;
    }
#pragma unroll
    for (int rx = 0; rx < 2; ++rx)
#pragma unroll
      for (int ry = 0; ry < 2; ++ry) {
        const float* rc = rcw[rx * 2 + ry];
        int X = 8 * tx + 2 * ix + rx, Y = 8 * ty + 2 * iy + ry;
#pragma unroll
        for (int o = 0; o < 9; ++o) {
          float s0 = 0.f, s1 = 0.f, s2 = 0.f, s3 = 0.f;
#pragma unroll
          for (int i = 0; i < 18; ++i) {
            float w = rc[i * 9 + o];
            s0 += cat[i][0] * w; s1 += cat[i][1] * w; s2 += cat[i][2] * w; s3 += cat[i][3] * w;
          }
          *reinterpret_cast<float4*>(
              &out[((((long)b * 9 + o) * 64 + X) * 64 + Y) * 64 + tq * 4]) =
              make_float4(s0, s1, s2, s3);
        }
      }
  }
}

extern "C" void kernel_launch(void* const* d_in, const int* in_sizes, int n_in, void* d_out,
                              int out_size, void* d_ws, size_t ws_size, hipStream_t stream) {
  (void)in_sizes; (void)n_in; (void)out_size; (void)ws_size;
  const float* x = (const float*)d_in[0];
  const float* aw[4] = {(const float*)d_in[1], (const float*)d_in[2], (const float*)d_in[3],
                        (const float*)d_in[4]};
  const float* a_low = (const float*)d_in[5];
  const float* a_lob = (const float*)d_in[6];
  const float* bw[4] = {(const float*)d_in[7], (const float*)d_in[8], (const float*)d_in[9],
                        (const float*)d_in[10]};
  const float* b_low = (const float*)d_in[11];
  const float* b_lob = (const float*)d_in[12];
  const float* cw[4] = {(const float*)d_in[13], (const float*)d_in[14], (const float*)d_in[15],
                        (const float*)d_in[16]};
  const float* c_low = (const float*)d_in[17];
  const float* c_lob = (const float*)d_in[18];
  const float* t0w = (const float*)d_in[19];
  const float* t0b = (const float*)d_in[20];
  const float* ecs = (const float*)d_in[21];
  const float* ecd = (const float*)d_in[22];
  const float* rcee = (const float*)d_in[23];
  const float* rceo = (const float*)d_in[24];
  const float* rcoe = (const float*)d_in[25];
  const float* rcoo = (const float*)d_in[26];

  Levels lv;
  {
    int zt = 0, zxy = 0, gh = 0;
    static const int uoff[6] = {0, 9437184, 11796480, 12386304, 12533760, 12570624};
    for (int lev = 0; lev < 6; ++lev) {
      int n = 32 >> lev;
      int kn = n < 10 ? n : 10;
      lv.n[lev] = n;
      lv.kn[lev] = kn;
      lv.zt_off[lev] = zt;
      lv.zxy_off[lev] = zxy;
      lv.z6_off[lev] = zt;
      lv.u_off[lev] = uoff[lev];
      lv.gstart[lev] = gh;
      lv.scale[lev] = 1.f / sqrtf((float)(n * n * 64));
      zt += NB * 9 * n * n * 10;
      zxy += NB * 9 * kn * kn * 10;
      gh += (NB * n * n + 3) / 4;
    }
    lv.gstart[6] = gh;
  }

  char* base = (char*)d_ws;
  size_t ob = 0;
  auto allocF = [&](size_t ne) { float* p = (float*)(base + ob); ob += ne * 4; return p; };
  auto allocH = [&](size_t ne) {
    __half* p = (__half*)(base + ob);
    ob += ((ne + 1) & ~(size_t)1) * 2;
    return p;
  };
  float* twt = allocF(640);
  float* twx = allocF(3840);
  float* Zt_d = allocF(1965600);
  float* Zt_s = allocF(1965600);
  float* Zxy_d = allocF(410400);
  float* Zxy_s = allocF(410400);
  __half* s_a = allocH(9437184);
  __half* s_b = allocH(9437184);
  __half* Z6a = allocH(1965600);
  __half* Z6b = allocH(1965600);
  __half* Z6c = allocH(1965600);
  __half* Ud = allocH(12579840);
  __half* Us = allocH(12579840);

  k_init<<<1, 256, 0, stream>>>(twt, twx);

  for (int lev = 0; lev < 6; ++lev) {
    int n = 32 >> lev;
    int nblk = (NB * n * n + 15) / 16;
    __half* s_cur = (lev & 1) ? s_b : s_a;
    float* ztd = Zt_d + lv.zt_off[lev];
    float* zts = Zt_s + lv.zt_off[lev];
    if (lev == 0)
      k_wavdft<float><<<nblk, 256, 0, stream>>>(x, ecd, ecs, s_cur, ztd, zts, twt, n,
                                                lv.scale[lev]);
    else
      k_wavdft<__half><<<nblk, 256, 0, stream>>>((lev & 1) ? s_a : s_b, ecd, ecs, s_cur, ztd,
                                                 zts, twt, n, lv.scale[lev]);
  }

  k_bc_all<<<6 * 288, 256, 0, stream>>>(Zt_d, Zt_s, Zxy_d, Zxy_s, twx, lv);
  WArgs wa;
  for (int j = 0; j < 4; ++j) { wa.w[j] = aw[j]; wa.w[4 + j] = bw[j]; wa.w[8 + j] = cw[j]; }
  k_efmix_all<<<6 * 432, 256, 0, stream>>>(Zxy_d, Zxy_s, Z6a, Z6b, Z6c, wa, twx, lv);
  k_gh3_all<<<lv.gstart[6], 256, 0, stream>>>(Z6a, Z6b, Z6c, a_low, a_lob, b_low, b_lob, c_low,
                                              c_lob, Ud, Us, twt, lv);

  k_recon_fused<<<NB * 64, 256, 0, stream>>>(s_b, t0w, t0b, Ud, Us, rcee, rceo, rcoe, rcoo,
                                             (float*)d_out, lv);
}

// Round 5
// 285.004 us; speedup vs baseline: 1.5213x; 1.5213x over previous
//
#include <hip/hip_runtime.h>
#include <hip/hip_fp16.h>
#include <math.h>

#define NB 16
#define PI2 6.28318530717958647692f

struct Levels {
  int n[6], kn[6];
  int zt_off[6];   // float elements
  int zxy_off[6];  // float elements
  int z6_off[6];   // half elements
  int u_off[6];    // half elements
  int gstart[7];
  float scale[6];
};
struct WArgs {
  const float* w[12];
};

// ---------------- small load/store helpers ----------------
__device__ inline float4 ld4g(const float* p) { return *reinterpret_cast<const float4*>(p); }
__device__ inline float4 ld4g(const __half* p) {
  float2 raw = *reinterpret_cast<const float2*>(p);
  union { float2 f; __half2 h[2]; } u;
  u.f = raw;
  float2 a = __half22float2(u.h[0]), b = __half22float2(u.h[1]);
  return make_float4(a.x, a.y, b.x, b.y);
}

// ---------------- twiddle tables ----------------
__global__ __launch_bounds__(256) void k_init(float* __restrict__ twt, float* __restrict__ twx) {
  int tid = threadIdx.x;
  for (int i = tid; i < 5 * 64; i += 256) {
    int k = i >> 6, t = i & 63;
    float ang = (float)((k * t) & 63) * (PI2 / 64.f);
    float s, c;
    sincosf(ang, &s, &c);
    twt[2 * i] = c;
    twt[2 * i + 1] = s;
  }
  for (int lev = 0; lev < 6; ++lev) {
    int n = 32 >> lev;
    int kn = n < 10 ? n : 10;
    float* tx = twx + lev * 640;
    for (int i = tid; i < kn * n; i += 256) {
      int j = i / n, m = i % n;
      int k = (kn < 10) ? j : (j < 5 ? j : n - 10 + j);
      float ang = (float)((k * m) % n) * (PI2 / (float)n);
      float s, c;
      sincosf(ang, &s, &c);
      tx[2 * i] = c;
      tx[2 * i + 1] = s;
    }
  }
}

// ---------------- fused wavelet analysis + forward t-DFT (LDS-staged) -----------
// xin: [NB][9][2n][2n][64] -> sout (half), Zd/Zs: [NB][9][n][n][5] cplx
template <typename T>
__global__ __launch_bounds__(256) void k_wavdft(const T* __restrict__ xin,
                                                const float* __restrict__ ecd,
                                                const float* __restrict__ ecs,
                                                __half* __restrict__ sout,
                                                float* __restrict__ Zd, float* __restrict__ Zs,
                                                const float* __restrict__ twt, int n,
                                                float scale) {
  __shared__ float V[72 * 65];  // (p*18 + ds*9 + ch)*65 + t
  __shared__ float tw[640];
  int tid = threadIdx.x;
  for (int i = tid; i < 640; i += 256) tw[i] = twt[i];
  long pos0 = (long)blockIdx.x * 4;
  long total = (long)NB * n * n;
  int p = tid >> 6, t = tid & 63;
  long pos = pos0 + p;
  if (pos < total) {
    int b = (int)(pos / (n * n));
    int rem = (int)(pos % (n * n));
    int xp = rem / n, yp = rem % n;
    int n2 = 2 * n;
    const T* xb = xin + (long)b * 9 * n2 * n2 * 64;
    float dacc[9], sacc[9];
#pragma unroll
    for (int o = 0; o < 9; ++o) { dacc[o] = 0.f; sacc[o] = 0.f; }
#pragma unroll
    for (int q = 0; q < 4; ++q) {
      int X = 2 * xp + (q >> 1), Y = 2 * yp + (q & 1);
      const T* xq = xb + ((long)X * n2 + Y) * 64 + t;
#pragma unroll
      for (int i = 0; i < 9; ++i) {
        float v = (float)xq[(long)i * n2 * n2 * 64];
#pragma unroll
        for (int o = 0; o < 9; ++o) {
          dacc[o] += v * ecd[(q * 9 + i) * 9 + o];
          sacc[o] += v * ecs[(q * 9 + i) * 9 + o];
        }
      }
    }
    long cs = (long)n * n * 64;
    __half* sp = sout + (long)b * 9 * cs + (long)rem * 64 + t;
#pragma unroll
    for (int o = 0; o < 9; ++o) {
      sp[o * cs] = __float2half(sacc[o]);
      V[(p * 18 + o) * 65 + t] = dacc[o];
      V[(p * 18 + 9 + o) * 65 + t] = sacc[o];
    }
  }
  __syncthreads();
  // phase 2: 5-mode t-DFT from LDS. tasks: (p, ds, ch, k) = 4*2*9*5 = 360
  for (int idx = tid; idx < 360; idx += 256) {
    int k = idx % 5;
    int ch = (idx / 5) % 9;
    int ds = (idx / 45) & 1;
    int pp = idx / 90;
    long pos2 = pos0 + pp;
    if (pos2 >= total) continue;
    const float* vr = &V[(pp * 18 + ds * 9 + ch) * 65];
    const float2* tw2 = reinterpret_cast<const float2*>(&tw[2 * (k * 64)]);
    float sr = 0.f, si = 0.f;
#pragma unroll 8
    for (int tt = 0; tt < 64; ++tt) {
      float v = vr[tt];
      float2 cs2 = tw2[tt];
      sr += v * cs2.x;
      si -= v * cs2.y;
    }
    int b = (int)(pos2 / (n * n));
    int rem = (int)(pos2 % (n * n));
    float* o = (ds ? Zs : Zd) + ((long)(b * 9 + ch) * n * n + rem) * 10 + 2 * k;
    o[0] = sr * scale;
    o[1] = si * scale;
  }
}

// ---------------- all-level forward y-DFT then x-DFT ----------------
__global__ __launch_bounds__(256) void k_bc_all(const float* __restrict__ Zt_d,
                                                const float* __restrict__ Zt_s,
                                                float* __restrict__ Zxy_d,
                                                float* __restrict__ Zxy_s,
                                                const float* __restrict__ twx_all, Levels lv) {
  __shared__ float S1[3200];
  __shared__ float tx[640];
  int lev = blockIdx.x / 288;
  int r = blockIdx.x % 288;
  int ds = r / 144, bc = r % 144;
  int n = lv.n[lev], kn = lv.kn[lev];
  int tid = threadIdx.x;
  const float* twx = twx_all + lev * 640;
  for (int i = tid; i < kn * n * 2; i += 256) tx[i] = twx[i];
  __syncthreads();
  const float* in = (ds ? Zt_s : Zt_d) + lv.zt_off[lev] + (long)bc * n * n * 10;
  float* out = (ds ? Zxy_s : Zxy_d) + lv.zxy_off[lev] + (long)bc * kn * kn * 10;
  int s1n = n * kn * 5;
  for (int idx = tid; idx < s1n; idx += 256) {
    int kz = idx % 5, jy = (idx / 5) % kn, x = idx / (5 * kn);
    float sr = 0.f, si = 0.f;
    const float2* row2 = reinterpret_cast<const float2*>(in + (long)x * n * 10);
    for (int y = 0; y < n; ++y) {
      float2 z = row2[y * 5 + kz];
      float2 cs2 = *reinterpret_cast<const float2*>(&tx[2 * (jy * n + y)]);
      sr += z.x * cs2.x + z.y * cs2.y;
      si += z.y * cs2.x - z.x * cs2.y;
    }
    *reinterpret_cast<float2*>(&S1[2 * idx]) = make_float2(sr, si);
  }
  __syncthreads();
  int s2n = kn * kn * 5;
  for (int idx = tid; idx < s2n; idx += 256) {
    int kz = idx % 5, jy = (idx / 5) % kn, jx = idx / (5 * kn);
    float sr = 0.f, si = 0.f;
    for (int x = 0; x < n; ++x) {
      float2 z = *reinterpret_cast<const float2*>(&S1[2 * ((x * kn + jy) * 5 + kz)]);
      float2 cs2 = *reinterpret_cast<const float2*>(&tx[2 * (jx * n + x)]);
      sr += z.x * cs2.x + z.y * cs2.y;
      si += z.y * cs2.x - z.x * cs2.y;
    }
    *reinterpret_cast<float2*>(&out[2 * idx]) = make_float2(sr, si);
  }
}

// ---------------- all-level fused mode-mix + inverse expand x,y ----------------
__global__ __launch_bounds__(256) void k_efmix_all(const float* __restrict__ Zxy_d,
                                                   const float* __restrict__ Zxy_s,
                                                   __half* __restrict__ Z6a,
                                                   __half* __restrict__ Z6b,
                                                   __half* __restrict__ Z6c, WArgs wa,
                                                   const float* __restrict__ twx_all,
                                                   Levels lv) {
  __shared__ float zin[9000];
  __shared__ float zm[1000];
  __shared__ float S1[3200];
  __shared__ float tx[640];
  int lev = blockIdx.x / 432;
  int r = blockIdx.x % 432;
  int batch = r / 144;
  int rr = r % 144;
  int b = rr / 9, o = rr % 9;
  int n = lv.n[lev], kn = lv.kn[lev];
  int nm = kn * kn * 5;
  int tid = threadIdx.x;
  const float* twx = twx_all + lev * 640;
  const float* in = (batch == 1 ? Zxy_s : Zxy_d) + lv.zxy_off[lev] + (long)b * 9 * nm * 2;
  __half* out = (batch == 0 ? Z6a : batch == 1 ? Z6b : Z6c) + lv.z6_off[lev] +
                ((long)(b * 9 + o)) * n * n * 10;
  for (int i = tid; i < kn * n * 2; i += 256) tx[i] = twx[i];
  for (int i = tid; i < 9 * nm; i += 256)
    reinterpret_cast<float2*>(zin)[i] = reinterpret_cast<const float2*>(in)[i];
  __syncthreads();
  int l1 = (5 < n / 2 + 1) ? 5 : n / 2 + 1;
  for (int m = tid; m < nm; m += 256) {
    int kz = m % 5, jy = (m / 5) % kn, jx = m / (5 * kn);
    int kx = (kn < 10) ? jx : (jx < 5 ? jx : n - 10 + jx);
    int ky = (kn < 10) ? jy : (jy < 5 ? jy : n - 10 + jy);
    bool lx = kx < l1, hx = kx >= n - l1, ly = ky < l1, hy = ky >= n - l1;
    const float* wsel;
    int wx, wy;
    if (hx && hy) { wsel = wa.w[batch * 4 + 3]; wx = kx - (n - l1); wy = ky - (n - l1); }
    else if (lx && hy) { wsel = wa.w[batch * 4 + 2]; wx = kx; wy = ky - (n - l1); }
    else if (hx && ly) { wsel = wa.w[batch * 4 + 1]; wx = kx - (n - l1); wy = ky; }
    else { wsel = wa.w[batch * 4 + 0]; wx = kx; wy = ky; }
    const float* wp = wsel + o * 250 + wx * 50 + wy * 10 + kz * 2;
    float sr = 0.f, si = 0.f;
#pragma unroll
    for (int i = 0; i < 9; ++i) {
      float2 z = *reinterpret_cast<const float2*>(&zin[(i * nm + m) * 2]);
      float2 w2 = *reinterpret_cast<const float2*>(&wp[i * 2250]);
      sr += z.x * w2.x - z.y * w2.y;
      si += z.x * w2.y + z.y * w2.x;
    }
    *reinterpret_cast<float2*>(&zm[2 * m]) = make_float2(sr, si);
  }
  __syncthreads();
  int s1n = n * kn * 5;
  for (int idx = tid; idx < s1n; idx += 256) {
    int kz = idx % 5, jy = (idx / 5) % kn, x = idx / (5 * kn);
    float sr = 0.f, si = 0.f;
    for (int jx = 0; jx < kn; ++jx) {
      float2 z = *reinterpret_cast<const float2*>(&zm[2 * ((jx * kn + jy) * 5 + kz)]);
      float2 cs2 = *reinterpret_cast<const float2*>(&tx[2 * (jx * n + x)]);
      sr += z.x * cs2.x - z.y * cs2.y;
      si += z.x * cs2.y + z.y * cs2.x;
    }
    *reinterpret_cast<float2*>(&S1[2 * idx]) = make_float2(sr, si);
  }
  __syncthreads();
  int s2n = n * n * 5;
  for (int idx = tid; idx < s2n; idx += 256) {
    int kz = idx % 5, y = (idx / 5) % n, x = idx / (5 * n);
    float sr = 0.f, si = 0.f;
    for (int jy = 0; jy < kn; ++jy) {
      float2 z = *reinterpret_cast<const float2*>(&S1[2 * ((x * kn + jy) * 5 + kz)]);
      float2 cs2 = *reinterpret_cast<const float2*>(&tx[2 * (jy * n + y)]);
      sr += z.x * cs2.x - z.y * cs2.y;
      si += z.x * cs2.y + z.y * cs2.x;
    }
    *reinterpret_cast<__half2*>(out + 2 * idx) = __floats2half2_rn(sr, si);
  }
}

// ---------------- all-level inverse-t(c2r) + ReLU + lo conv ----------------
__global__ __launch_bounds__(256) void k_gh3_all(const __half* __restrict__ Z6a,
                                                 const __half* __restrict__ Z6b,
                                                 const __half* __restrict__ Z6c,
                                                 const float* __restrict__ a_low,
                                                 const float* __restrict__ a_lob,
                                                 const float* __restrict__ b_low,
                                                 const float* __restrict__ b_lob,
                                                 const float* __restrict__ c_low,
                                                 const float* __restrict__ c_lob,
                                                 __half* __restrict__ Ud,
                                                 __half* __restrict__ Us,
                                                 const float* __restrict__ twt, Levels lv) {
  __shared__ float tw[640];
  __shared__ float zz[3][4][90];
  int tid = threadIdx.x;
  for (int i = tid; i < 640; i += 256) tw[i] = twt[i];
  int lev = 0;
  while (lev < 5 && (int)blockIdx.x >= lv.gstart[lev + 1]) ++lev;
  int n = lv.n[lev];
  float scale = lv.scale[lev];
  long pos0 = (long)(blockIdx.x - lv.gstart[lev]) * 4;
  long total = (long)NB * n * n;
  const __half* zbuf[3] = {Z6a + lv.z6_off[lev], Z6b + lv.z6_off[lev], Z6c + lv.z6_off[lev]};
  for (int i = tid; i < 540; i += 256) {
    int bi = i / 180;
    int rr2 = i % 180;
    int p = rr2 / 45;
    int q = rr2 % 45;
    int ch = q / 5, kz = q % 5;
    long pos = pos0 + p;
    if (pos < total) {
      int b = (int)(pos / (n * n));
      int rem = (int)(pos % (n * n));
      const __half2* src = reinterpret_cast<const __half2*>(
          zbuf[bi] + ((long)(b * 9 + ch) * n * n + rem) * 10 + 2 * kz);
      float2 f = __half22float2(*src);
      *reinterpret_cast<float2*>(&zz[bi][p][ch * 10 + 2 * kz]) = f;
    }
  }
  __syncthreads();
  int p = tid / 64, t = tid & 63;
  long pos = pos0 + p;
  if (pos >= total) return;
  int b = (int)(pos / (n * n));
  int rem = (int)(pos % (n * n));
  float tc[4], tsn[4];
#pragma unroll
  for (int k = 1; k < 5; ++k) {
    float2 cs2 = *reinterpret_cast<const float2*>(&tw[2 * (k * 64 + t)]);
    tc[k - 1] = cs2.x;
    tsn[k - 1] = cs2.y;
  }
  float rva[9], rvb[9], rvc[9];
#pragma unroll
  for (int i = 0; i < 9; ++i) {
    const float* za = &zz[0][p][i * 10];
    const float* zb = &zz[1][p][i * 10];
    const float* zc = &zz[2][p][i * 10];
    float va = za[0], vb = zb[0], vc = zc[0];
#pragma unroll
    for (int k = 1; k < 5; ++k) {
      float2 za2 = *reinterpret_cast<const float2*>(&za[2 * k]);
      float2 zb2 = *reinterpret_cast<const float2*>(&zb[2 * k]);
      float2 zc2 = *reinterpret_cast<const float2*>(&zc[2 * k]);
      va += 2.f * (za2.x * tc[k - 1] - za2.y * tsn[k - 1]);
      vb += 2.f * (zb2.x * tc[k - 1] - zb2.y * tsn[k - 1]);
      vc += 2.f * (zc2.x * tc[k - 1] - zc2.y * tsn[k - 1]);
    }
    rva[i] = fmaxf(va * scale, 0.f);
    rvb[i] = fmaxf(vb * scale, 0.f);
    rvc[i] = fmaxf(vc * scale, 0.f);
  }
  long cs = (long)n * n * 64;
  long ob = (long)b * 9 * cs + (long)rem * 64 + t;
  __half* ud = Ud + lv.u_off[lev];
  __half* us = Us + lv.u_off[lev];
#pragma unroll
  for (int o = 0; o < 9; ++o) {
    float du = a_lob[o] + b_lob[o];
    float usv = c_lob[o];
#pragma unroll
    for (int i = 0; i < 9; ++i) {
      du += a_low[o * 9 + i] * rva[i] + b_low[o * 9 + i] * rvb[i];
      usv += c_low[o * 9 + i] * rvc[i];
    }
    ud[ob + o * cs] = __float2half(du);
    us[ob + o * cs] = __float2half(usv);
  }
}

// ---------------- single-pos recon step helper ----------------
__device__ inline void step1pos(const float* __restrict__ in, float* __restrict__ outp,
                                const __half* __restrict__ us, const __half* __restrict__ ud,
                                long chs, const float* __restrict__ rc, int t) {
  float cat[18];
#pragma unroll
  for (int i = 0; i < 9; ++i) cat[i] = in[i * 64 + t] + __half2float(us[chs * i + t]);
#pragma unroll
  for (int i = 0; i < 9; ++i) cat[9 + i] = __half2float(ud[chs * i + t]);
#pragma unroll
  for (int o = 0; o < 9; ++o) {
    float s = 0.f;
#pragma unroll
    for (int i = 0; i < 18; ++i) s += cat[i] * rc[i * 9 + o];
    outp[o * 64 + t] = s;
  }
}

// ---------------- fully fused reconstruction: t0 + all 6 levels ----------------
__global__ __launch_bounds__(256) void k_recon_fused(
    const __half* __restrict__ s5, const float* __restrict__ t0w,
    const float* __restrict__ t0b, const __half* __restrict__ Ud,
    const __half* __restrict__ Us, const float* __restrict__ rcee,
    const float* __restrict__ rceo, const float* __restrict__ roe_,
    const float* __restrict__ roo_, float* __restrict__ out, Levels lv) {
  __shared__ float A[576];
  __shared__ float Bq[576];
  __shared__ float mid[4 * 580];
  __shared__ float big[16 * 580];
  int tid = threadIdx.x;
  int b = blockIdx.x >> 6;
  int T = blockIdx.x & 63;
  int tx = T >> 3, ty = T & 7;
  const float* rcw[4] = {rcee, rceo, roe_, roo_};

  if (tid < 64) {
    int t = tid;
    float v[9];
#pragma unroll
    for (int i = 0; i < 9; ++i) v[i] = __half2float(s5[((long)b * 9 + i) * 64 + t]);
#pragma unroll
    for (int o = 0; o < 9; ++o) {
      float s = t0b[o];
#pragma unroll
      for (int i = 0; i < 9; ++i) s += t0w[o * 9 + i] * v[i];
      A[o * 64 + t] = s;
    }
  }
  __syncthreads();
  if (tid < 64) {
    int t = tid;
    int sel = ((tx >> 2) & 1) * 2 + ((ty >> 2) & 1);
    long base = lv.u_off[5] + (long)b * 9 * 64;
    step1pos(A, Bq, Us + base, Ud + base, 64, rcw[sel], t);
  }
  __syncthreads();
  if (tid < 64) {
    int t = tid;
    int ip = (tx >> 2) * 2 + (ty >> 2);
    int sel = ((tx >> 1) & 1) * 2 + ((ty >> 1) & 1);
    long base = lv.u_off[4] + ((long)b * 9 * 4 + ip) * 64;
    step1pos(Bq, A, Us + base, Ud + base, 4 * 64, rcw[sel], t);
  }
  __syncthreads();
  if (tid < 64) {
    int t = tid;
    int ip = (tx >> 1) * 4 + (ty >> 1);
    int sel = (tx & 1) * 2 + (ty & 1);
    long base = lv.u_off[3] + ((long)b * 9 * 16 + ip) * 64;
    step1pos(A, Bq, Us + base, Ud + base, 16 * 64, rcw[sel], t);
  }
  __syncthreads();
  {
    int q = tid >> 6, t = tid & 63;
    int ip = tx * 8 + ty;
    long base = lv.u_off[2] + ((long)b * 9 * 64 + ip) * 64;
    step1pos(Bq, &mid[q * 580], Us + base, Ud + base, 64 * 64, rcw[q], t);
  }
  __syncthreads();
  {
    int pos16 = tid >> 4, tq = tid & 15;
    int ox = pos16 >> 2, oy = pos16 & 3;
    int q = (ox >> 1) * 2 + (oy >> 1);
    int gx = 2 * tx + (ox >> 1), gy = 2 * ty + (oy >> 1);
    int ip = gx * 16 + gy;
    long base = lv.u_off[1] + ((long)b * 9 * 256 + ip) * 64 + tq * 4;
    const float* rc = rcw[(ox & 1) * 2 + (oy & 1)];
    float cat[18][4];
#pragma unroll
    for (int i = 0; i < 9; ++i) {
      float4 m4 = *reinterpret_cast<const float4*>(&mid[q * 580 + i * 64 + tq * 4]);
      float4 u4 = ld4g(Us + base + (long)i * 256 * 64);
      cat[i][0] = m4.x + u4.x; cat[i][1] = m4.y + u4.y;
      cat[i][2] = m4.z + u4.z; cat[i][3] = m4.w + u4.w;
      float4 d4 = ld4g(Ud + base + (long)i * 256 * 64);
      cat[9 + i][0] = d4.x; cat[9 + i][1] = d4.y; cat[9 + i][2] = d4.z; cat[9 + i][3] = d4.w;
    }
#pragma unroll
    for (int o = 0; o < 9; ++o) {
      float s0 = 0.f, s1 = 0.f, s2 = 0.f, s3 = 0.f;
#pragma unroll
      for (int i = 0; i < 18; ++i) {
        float w = rc[i * 9 + o];
        s0 += cat[i][0] * w; s1 += cat[i][1] * w; s2 += cat[i][2] * w; s3 += cat[i][3] * w;
      }
      *reinterpret_cast<float4*>(&big[pos16 * 580 + o * 64 + tq * 4]) =
          make_float4(s0, s1, s2, s3);
    }
  }
  __syncthreads();
  {
    int q16 = tid >> 4, tq = tid & 15;
    int ix = q16 >> 2, iy = q16 & 3;
    int gx = 4 * tx + ix, gy = 4 * ty + iy;
    int ip = gx * 32 + gy;
    long base = lv.u_off[0] + ((long)b * 9 * 1024 + ip) * 64 + tq * 4;
    float cat[18][4];
#pragma unroll
    for (int i = 0; i < 9; ++i) {
      float4 m4 = *reinterpret_cast<const float4*>(&big[q16 * 580 + i * 64 + tq * 4]);
      float4 u4 = ld4g(Us + base + (long)i * 1024 * 64);
      cat[i][0] = m4.x + u4.x; cat[i][1] = m4.y + u4.y;
      cat[i][2] = m4.z + u4.z; cat[i][3] = m4.w + u4.w;
      float4 d4 = ld4g(Ud + base + (long)i * 1024 * 64);
      cat[9 + i][0] = d4.x; cat[9 + i][1] = d4.y; cat[9 + i][2] = d4.z; cat[9 + i][3] = d4.w;
    }
#pragma unroll
    for (int rx = 0; rx < 2; ++rx)
#pragma unroll
      for (int ry = 0; ry < 2; ++ry) {
        const float* rc = rcw[rx * 2 + ry];
        int X = 8 * tx + 2 * ix + rx, Y = 8 * ty + 2 * iy + ry;
#pragma unroll
        for (int o = 0; o < 9; ++o) {
          float s0 = 0.f, s1 = 0.f, s2 = 0.f, s3 = 0.f;
#pragma unroll
          for (int i = 0; i < 18; ++i) {
            float w = rc[i * 9 + o];
            s0 += cat[i][0] * w; s1 += cat[i][1] * w; s2 += cat[i][2] * w; s3 += cat[i][3] * w;
          }
          *reinterpret_cast<float4*>(
              &out[((((long)b * 9 + o) * 64 + X) * 64 + Y) * 64 + tq * 4]) =
              make_float4(s0, s1, s2, s3);
        }
      }
  }
}

extern "C" void kernel_launch(void* const* d_in, const int* in_sizes, int n_in, void* d_out,
                              int out_size, void* d_ws, size_t ws_size, hipStream_t stream) {
  (void)in_sizes; (void)n_in; (void)out_size; (void)ws_size;
  const float* x = (const float*)d_in[0];
  const float* aw[4] = {(const float*)d_in[1], (const float*)d_in[2], (const float*)d_in[3],
                        (const float*)d_in[4]};
  const float* a_low = (const float*)d_in[5];
  const float* a_lob = (const float*)d_in[6];
  const float* bw[4] = {(const float*)d_in[7], (const float*)d_in[8], (const float*)d_in[9],
                        (const float*)d_in[10]};
  const float* b_low = (const float*)d_in[11];
  const float* b_lob = (const float*)d_in[12];
  const float* cw[4] = {(const float*)d_in[13], (const float*)d_in[14], (const float*)d_in[15],
                        (const float*)d_in[16]};
  const float* c_low = (const float*)d_in[17];
  const float* c_lob = (const float*)d_in[18];
  const float* t0w = (const float*)d_in[19];
  const float* t0b = (const float*)d_in[20];
  const float* ecs = (const float*)d_in[21];
  const float* ecd = (const float*)d_in[22];
  const float* rcee = (const float*)d_in[23];
  const float* rceo = (const float*)d_in[24];
  const float* rcoe = (const float*)d_in[25];
  const float* rcoo = (const float*)d_in[26];

  Levels lv;
  {
    int zt = 0, zxy = 0, gh = 0;
    static const int uoff[6] = {0, 9437184, 11796480, 12386304, 12533760, 12570624};
    for (int lev = 0; lev < 6; ++lev) {
      int n = 32 >> lev;
      int kn = n < 10 ? n : 10;
      lv.n[lev] = n;
      lv.kn[lev] = kn;
      lv.zt_off[lev] = zt;
      lv.zxy_off[lev] = zxy;
      lv.z6_off[lev] = zt;
      lv.u_off[lev] = uoff[lev];
      lv.gstart[lev] = gh;
      lv.scale[lev] = 1.f / sqrtf((float)(n * n * 64));
      zt += NB * 9 * n * n * 10;
      zxy += NB * 9 * kn * kn * 10;
      gh += (NB * n * n + 3) / 4;
    }
    lv.gstart[6] = gh;
  }

  char* base = (char*)d_ws;
  size_t ob = 0;
  auto allocF = [&](size_t ne) { float* p = (float*)(base + ob); ob += ne * 4; return p; };
  auto allocH = [&](size_t ne) {
    __half* p = (__half*)(base + ob);
    ob += ((ne + 1) & ~(size_t)1) * 2;
    return p;
  };
  float* twt = allocF(640);
  float* twx = allocF(3840);
  float* Zt_d = allocF(1965600);
  float* Zt_s = allocF(1965600);
  float* Zxy_d = allocF(410400);
  float* Zxy_s = allocF(410400);
  __half* s_a = allocH(9437184);
  __half* s_b = allocH(9437184);
  __half* Z6a = allocH(1965600);
  __half* Z6b = allocH(1965600);
  __half* Z6c = allocH(1965600);
  __half* Ud = allocH(12579840);
  __half* Us = allocH(12579840);

  k_init<<<1, 256, 0, stream>>>(twt, twx);

  for (int lev = 0; lev < 6; ++lev) {
    int n = 32 >> lev;
    int nblk = (NB * n * n + 3) / 4;
    __half* s_cur = (lev & 1) ? s_b : s_a;
    float* ztd = Zt_d + lv.zt_off[lev];
    float* zts = Zt_s + lv.zt_off[lev];
    if (lev == 0)
      k_wavdft<float><<<nblk, 256, 0, stream>>>(x, ecd, ecs, s_cur, ztd, zts, twt, n,
                                                lv.scale[lev]);
    else
      k_wavdft<__half><<<nblk, 256, 0, stream>>>((lev & 1) ? s_a : s_b, ecd, ecs, s_cur, ztd,
                                                 zts, twt, n, lv.scale[lev]);
  }

  k_bc_all<<<6 * 288, 256, 0, stream>>>(Zt_d, Zt_s, Zxy_d, Zxy_s, twx, lv);
  WArgs wa;
  for (int j = 0; j < 4; ++j) { wa.w[j] = aw[j]; wa.w[4 + j] = bw[j]; wa.w[8 + j] = cw[j]; }
  k_efmix_all<<<6 * 432, 256, 0, stream>>>(Zxy_d, Zxy_s, Z6a, Z6b, Z6c, wa, twx, lv);
  k_gh3_all<<<lv.gstart[6], 256, 0, stream>>>(Z6a, Z6b, Z6c, a_low, a_lob, b_low, b_lob, c_low,
                                              c_lob, Ud, Us, twt, lv);

  k_recon_fused<<<NB * 64, 256, 0, stream>>>(s_b, t0w, t0b, Ud, Us, rcee, rceo, rcoe, rcoo,
                                             (float*)d_out, lv);
}

// Round 6
// 264.952 us; speedup vs baseline: 1.6364x; 1.0757x over previous
//
#include <hip/hip_runtime.h>
#include <hip/hip_fp16.h>
#include <math.h>

#define NB 16
#define PI2 6.28318530717958647692f

struct Levels {
  int n[6], kn[6];
  int zt_off[6];   // float elements
  int zxy_off[6];  // float elements
  int z6_off[6];   // half elements
  int u_off[6];    // half elements
  int gstart[7];
  float scale[6];
};
struct WArgs {
  const float* w[12];
};

// ---------------- small load/store helpers ----------------
__device__ inline float4 ld4g(const float* p) { return *reinterpret_cast<const float4*>(p); }
__device__ inline float4 ld4g(const __half* p) {
  float2 raw = *reinterpret_cast<const float2*>(p);
  union { float2 f; __half2 h[2]; } u;
  u.f = raw;
  float2 a = __half22float2(u.h[0]), b = __half22float2(u.h[1]);
  return make_float4(a.x, a.y, b.x, b.y);
}

// ---------------- twiddle tables ----------------
__global__ __launch_bounds__(256) void k_init(float* __restrict__ twt, float* __restrict__ twx) {
  int tid = threadIdx.x;
  for (int i = tid; i < 5 * 64; i += 256) {
    int k = i >> 6, t = i & 63;
    float ang = (float)((k * t) & 63) * (PI2 / 64.f);
    float s, c;
    sincosf(ang, &s, &c);
    twt[2 * i] = c;
    twt[2 * i + 1] = s;
  }
  for (int lev = 0; lev < 6; ++lev) {
    int n = 32 >> lev;
    int kn = n < 10 ? n : 10;
    float* tx = twx + lev * 640;
    for (int i = tid; i < kn * n; i += 256) {
      int j = i / n, m = i % n;
      int k = (kn < 10) ? j : (j < 5 ? j : n - 10 + j);
      float ang = (float)((k * m) % n) * (PI2 / (float)n);
      float s, c;
      sincosf(ang, &s, &c);
      tx[2 * i] = c;
      tx[2 * i + 1] = s;
    }
  }
}

// ---------------- fused wavelet analysis + forward t-DFT ----------------
// phase1: quadrant contraction into LDS V (stride 66)
// phase2: register-twiddle partial products + LDS reduce (no shfl, no divergence)
template <typename T>
__global__ __launch_bounds__(256) void k_wavdft(const T* __restrict__ xin,
                                                const float* __restrict__ ecd,
                                                const float* __restrict__ ecs,
                                                __half* __restrict__ sout,
                                                float* __restrict__ Zd, float* __restrict__ Zs,
                                                const float* __restrict__ twt, int n,
                                                float scale) {
  __shared__ float V[72 * 66];     // (p*18 + ds*9 + ch)*66 + t
  __shared__ float Vp[36 * 160];   // [row(p*9+ch)][10][16]
  __shared__ float tw[640];
  int tid = threadIdx.x;
  for (int i = tid; i < 640; i += 256) tw[i] = twt[i];
  long pos0 = (long)blockIdx.x * 4;
  long total = (long)NB * n * n;
  long nn = (long)n * n;
  int p = tid >> 6, t = tid & 63;
  long pos = pos0 + p;
  if (pos < total) {
    int b = (int)(pos / nn);
    int rem = (int)(pos % nn);
    int xp = rem / n, yp = rem % n;
    int n2 = 2 * n;
    const T* xb = xin + (long)b * 9 * n2 * n2 * 64;
    float dacc[9], sacc[9];
#pragma unroll
    for (int o = 0; o < 9; ++o) { dacc[o] = 0.f; sacc[o] = 0.f; }
#pragma unroll
    for (int q = 0; q < 4; ++q) {
      int X = 2 * xp + (q >> 1), Y = 2 * yp + (q & 1);
      const T* xq = xb + ((long)X * n2 + Y) * 64 + t;
#pragma unroll
      for (int i = 0; i < 9; ++i) {
        float v = (float)xq[(long)i * n2 * n2 * 64];
#pragma unroll
        for (int o = 0; o < 9; ++o) {
          dacc[o] += v * ecd[(q * 9 + i) * 9 + o];
          sacc[o] += v * ecs[(q * 9 + i) * 9 + o];
        }
      }
    }
    long cs = nn * 64;
    __half* sp = sout + (long)b * 9 * cs + (long)rem * 64 + t;
#pragma unroll
    for (int o = 0; o < 9; ++o) {
      sp[o * cs] = __float2half(sacc[o]);
      V[(p * 18 + o) * 66 + t] = dacc[o];
      V[(p * 18 + 9 + o) * 66 + t] = sacc[o];
    }
  }
  __syncthreads();
  // register twiddles for this thread's t-quad
  int tq = tid & 15;
  float tc[5][4], tsn[5][4];
#pragma unroll
  for (int k = 0; k < 5; ++k)
#pragma unroll
    for (int j = 0; j < 4; ++j) {
      tc[k][j] = tw[2 * (k * 64 + tq * 4 + j)];
      tsn[k][j] = tw[2 * (k * 64 + tq * 4 + j) + 1];
    }
#pragma unroll
  for (int ds = 0; ds < 2; ++ds) {
    // partial products: 36 rows x 16 t-quads
    for (int slot = tid; slot < 576; slot += 256) {
      int row = slot >> 4;  // p*9 + ch
      const float* vr = &V[((row / 9) * 18 + ds * 9 + (row % 9)) * 66 + tq * 4];
      float v0 = vr[0], v1 = vr[1], v2 = vr[2], v3 = vr[3];
      float* vp = &Vp[row * 160 + tq];
#pragma unroll
      for (int k = 0; k < 5; ++k) {
        float pr = v0 * tc[k][0] + v1 * tc[k][1] + v2 * tc[k][2] + v3 * tc[k][3];
        float pi = -(v0 * tsn[k][0] + v1 * tsn[k][1] + v2 * tsn[k][2] + v3 * tsn[k][3]);
        vp[(2 * k) * 16] = pr;
        vp[(2 * k + 1) * 16] = pi;
      }
    }
    __syncthreads();
    // reduce: 360 tasks (row, j)
    for (int task = tid; task < 360; task += 256) {
      int row = task / 10, j = task % 10;
      const float* vp = &Vp[row * 160 + j * 16];
      float4 a = *reinterpret_cast<const float4*>(vp);
      float4 b4 = *reinterpret_cast<const float4*>(vp + 4);
      float4 c4 = *reinterpret_cast<const float4*>(vp + 8);
      float4 d4 = *reinterpret_cast<const float4*>(vp + 12);
      float s = ((a.x + a.y) + (a.z + a.w)) + ((b4.x + b4.y) + (b4.z + b4.w)) +
                ((c4.x + c4.y) + (c4.z + c4.w)) + ((d4.x + d4.y) + (d4.z + d4.w));
      int pp = row / 9, ch = row % 9;
      long pos2 = pos0 + pp;
      if (pos2 < total) {
        int b = (int)(pos2 / nn);
        int rem = (int)(pos2 % nn);
        float* o = (ds ? Zs : Zd) + ((long)(b * 9 + ch) * nn + rem) * 10 + j;
        o[0] = s * scale;
      }
    }
    __syncthreads();
  }
}

// ---------------- all-level forward y-DFT then x-DFT (padded kz-12 layout) -------------
__global__ __launch_bounds__(256) void k_bc_all(const float* __restrict__ Zt_d,
                                                const float* __restrict__ Zt_s,
                                                float* __restrict__ Zxy_d,
                                                float* __restrict__ Zxy_s,
                                                const float* __restrict__ twx_all, Levels lv) {
  __shared__ float S1[3840];  // [x*kn+jy][12]
  __shared__ float tx[640];
  int lev = blockIdx.x / 288;
  int r = blockIdx.x % 288;
  int ds = r / 144, bc = r % 144;
  int n = lv.n[lev], kn = lv.kn[lev];
  int tid = threadIdx.x;
  const float* twx = twx_all + lev * 640;
  for (int i = tid; i < kn * n * 2; i += 256) tx[i] = twx[i];
  __syncthreads();
  const float* in = (ds ? Zt_s : Zt_d) + lv.zt_off[lev] + (long)bc * n * n * 10;
  float* out = (ds ? Zxy_s : Zxy_d) + lv.zxy_off[lev] + (long)bc * kn * kn * 10;
  // y-DFT: tasks (x, jy)
  int t1n = n * kn;
  for (int task = tid; task < t1n; task += 256) {
    int jy = task % kn, x = task / kn;
    float acc[10];
#pragma unroll
    for (int j = 0; j < 10; ++j) acc[j] = 0.f;
    const float2* row2 = reinterpret_cast<const float2*>(in + (long)x * n * 10);
    for (int y = 0; y < n; ++y) {
      float2 cs2 = *reinterpret_cast<const float2*>(&tx[2 * (jy * n + y)]);
#pragma unroll
      for (int kz = 0; kz < 5; ++kz) {
        float2 z = row2[y * 5 + kz];
        acc[2 * kz] += z.x * cs2.x + z.y * cs2.y;
        acc[2 * kz + 1] += z.y * cs2.x - z.x * cs2.y;
      }
    }
    float* s1 = &S1[(x * kn + jy) * 12];
#pragma unroll
    for (int j = 0; j < 10; ++j) s1[j] = acc[j];
  }
  __syncthreads();
  // x-DFT: tasks (jx, jy)
  int t2n = kn * kn;
  for (int task = tid; task < t2n; task += 256) {
    int jy = task % kn, jx = task / kn;
    float acc[10];
#pragma unroll
    for (int j = 0; j < 10; ++j) acc[j] = 0.f;
    for (int x = 0; x < n; ++x) {
      const float* zr = &S1[(x * kn + jy) * 12];
      float2 cs2 = *reinterpret_cast<const float2*>(&tx[2 * (jx * n + x)]);
#pragma unroll
      for (int kz = 0; kz < 5; ++kz) {
        float zx = zr[2 * kz], zy = zr[2 * kz + 1];
        acc[2 * kz] += zx * cs2.x + zy * cs2.y;
        acc[2 * kz + 1] += zy * cs2.x - zx * cs2.y;
      }
    }
    float* o = out + (jx * kn + jy) * 10;
#pragma unroll
    for (int j = 0; j < 10; ++j) o[j] = acc[j];
  }
}

// ---------------- all-level fused mode-mix + inverse expand x,y ----------------
__global__ __launch_bounds__(256) void k_efmix_all(const float* __restrict__ Zxy_d,
                                                   const float* __restrict__ Zxy_s,
                                                   __half* __restrict__ Z6a,
                                                   __half* __restrict__ Z6b,
                                                   __half* __restrict__ Z6c, WArgs wa,
                                                   const float* __restrict__ twx_all,
                                                   Levels lv) {
  __shared__ float zm[1200];   // [jx*kn+jy][12]
  __shared__ float S1[3840];   // [x*kn+jy][12]
  __shared__ float tx[640];
  int lev = blockIdx.x / 432;
  int r = blockIdx.x % 432;
  int batch = r / 144;
  int rr = r % 144;
  int b = rr / 9, o = rr % 9;
  int n = lv.n[lev], kn = lv.kn[lev];
  int nm = kn * kn * 5;
  int tid = threadIdx.x;
  const float* twx = twx_all + lev * 640;
  const float* in = (batch == 1 ? Zxy_s : Zxy_d) + lv.zxy_off[lev] + (long)b * 9 * nm * 2;
  const float2* in2 = reinterpret_cast<const float2*>(in);
  __half* out = (batch == 0 ? Z6a : batch == 1 ? Z6b : Z6c) + lv.z6_off[lev] +
                ((long)(b * 9 + o)) * n * n * 10;
  for (int i = tid; i < kn * n * 2; i += 256) tx[i] = twx[i];
  __syncthreads();
  // mix (global-direct input reads)
  int l1 = (5 < n / 2 + 1) ? 5 : n / 2 + 1;
  for (int m = tid; m < nm; m += 256) {
    int kz = m % 5, jy = (m / 5) % kn, jx = m / (5 * kn);
    int kx = (kn < 10) ? jx : (jx < 5 ? jx : n - 10 + jx);
    int ky = (kn < 10) ? jy : (jy < 5 ? jy : n - 10 + jy);
    bool lx = kx < l1, hx = kx >= n - l1, ly = ky < l1, hy = ky >= n - l1;
    const float* wsel;
    int wx, wy;
    if (hx && hy) { wsel = wa.w[batch * 4 + 3]; wx = kx - (n - l1); wy = ky - (n - l1); }
    else if (lx && hy) { wsel = wa.w[batch * 4 + 2]; wx = kx; wy = ky - (n - l1); }
    else if (hx && ly) { wsel = wa.w[batch * 4 + 1]; wx = kx - (n - l1); wy = ky; }
    else { wsel = wa.w[batch * 4 + 0]; wx = kx; wy = ky; }
    const float* wp = wsel + o * 250 + wx * 50 + wy * 10 + kz * 2;
    float sr = 0.f, si = 0.f;
#pragma unroll
    for (int i = 0; i < 9; ++i) {
      float2 z = in2[i * nm + m];
      float2 w2 = *reinterpret_cast<const float2*>(&wp[i * 2250]);
      sr += z.x * w2.x - z.y * w2.y;
      si += z.x * w2.y + z.y * w2.x;
    }
    zm[(jx * kn + jy) * 12 + 2 * kz] = sr;
    zm[(jx * kn + jy) * 12 + 2 * kz + 1] = si;
  }
  __syncthreads();
  // expand x: tasks (x, jy)
  int t1n = n * kn;
  for (int task = tid; task < t1n; task += 256) {
    int jy = task % kn, x = task / kn;
    float acc[10];
#pragma unroll
    for (int j = 0; j < 10; ++j) acc[j] = 0.f;
    for (int jx = 0; jx < kn; ++jx) {
      const float* zr = &zm[(jx * kn + jy) * 12];
      float2 cs2 = *reinterpret_cast<const float2*>(&tx[2 * (jx * n + x)]);
#pragma unroll
      for (int kz = 0; kz < 5; ++kz) {
        float zx = zr[2 * kz], zy = zr[2 * kz + 1];
        acc[2 * kz] += zx * cs2.x - zy * cs2.y;
        acc[2 * kz + 1] += zx * cs2.y + zy * cs2.x;
      }
    }
    float* s1 = &S1[(x * kn + jy) * 12];
#pragma unroll
    for (int j = 0; j < 10; ++j) s1[j] = acc[j];
  }
  __syncthreads();
  // expand y: tasks (x, y)
  int t2n = n * n;
  for (int task = tid; task < t2n; task += 256) {
    int y = task % n, x = task / n;
    float acc[10];
#pragma unroll
    for (int j = 0; j < 10; ++j) acc[j] = 0.f;
    for (int jy = 0; jy < kn; ++jy) {
      const float* zr = &S1[(x * kn + jy) * 12];
      float2 cs2 = *reinterpret_cast<const float2*>(&tx[2 * (jy * n + y)]);
#pragma unroll
      for (int kz = 0; kz < 5; ++kz) {
        float zx = zr[2 * kz], zy = zr[2 * kz + 1];
        acc[2 * kz] += zx * cs2.x - zy * cs2.y;
        acc[2 * kz + 1] += zx * cs2.y + zy * cs2.x;
      }
    }
    __half* op = out + (long)(x * n + y) * 10;
#pragma unroll
    for (int kz = 0; kz < 5; ++kz)
      *reinterpret_cast<__half2*>(op + 2 * kz) = __floats2half2_rn(acc[2 * kz], acc[2 * kz + 1]);
  }
}

// ---------------- all-level inverse-t(c2r) + ReLU + lo conv ----------------
__global__ __launch_bounds__(256) void k_gh3_all(const __half* __restrict__ Z6a,
                                                 const __half* __restrict__ Z6b,
                                                 const __half* __restrict__ Z6c,
                                                 const float* __restrict__ a_low,
                                                 const float* __restrict__ a_lob,
                                                 const float* __restrict__ b_low,
                                                 const float* __restrict__ b_lob,
                                                 const float* __restrict__ c_low,
                                                 const float* __restrict__ c_lob,
                                                 __half* __restrict__ Ud,
                                                 __half* __restrict__ Us,
                                                 const float* __restrict__ twt, Levels lv) {
  __shared__ float tw[640];
  __shared__ float zz[3][4][90];
  int tid = threadIdx.x;
  for (int i = tid; i < 640; i += 256) tw[i] = twt[i];
  int lev = 0;
  while (lev < 5 && (int)blockIdx.x >= lv.gstart[lev + 1]) ++lev;
  int n = lv.n[lev];
  float scale = lv.scale[lev];
  long pos0 = (long)(blockIdx.x - lv.gstart[lev]) * 4;
  long total = (long)NB * n * n;
  const __half* zbuf[3] = {Z6a + lv.z6_off[lev], Z6b + lv.z6_off[lev], Z6c + lv.z6_off[lev]};
  for (int i = tid; i < 540; i += 256) {
    int bi = i / 180;
    int rr2 = i % 180;
    int p = rr2 / 45;
    int q = rr2 % 45;
    int ch = q / 5, kz = q % 5;
    long pos = pos0 + p;
    if (pos < total) {
      int b = (int)(pos / (n * n));
      int rem = (int)(pos % (n * n));
      const __half2* src = reinterpret_cast<const __half2*>(
          zbuf[bi] + ((long)(b * 9 + ch) * n * n + rem) * 10 + 2 * kz);
      float2 f = __half22float2(*src);
      *reinterpret_cast<float2*>(&zz[bi][p][ch * 10 + 2 * kz]) = f;
    }
  }
  __syncthreads();
  int p = tid / 64, t = tid & 63;
  long pos = pos0 + p;
  if (pos >= total) return;
  int b = (int)(pos / (n * n));
  int rem = (int)(pos % (n * n));
  float tc[4], tsn[4];
#pragma unroll
  for (int k = 1; k < 5; ++k) {
    float2 cs2 = *reinterpret_cast<const float2*>(&tw[2 * (k * 64 + t)]);
    tc[k - 1] = cs2.x;
    tsn[k - 1] = cs2.y;
  }
  float rva[9], rvb[9], rvc[9];
#pragma unroll
  for (int i = 0; i < 9; ++i) {
    const float* za = &zz[0][p][i * 10];
    const float* zb = &zz[1][p][i * 10];
    const float* zc = &zz[2][p][i * 10];
    float va = za[0], vb = zb[0], vc = zc[0];
#pragma unroll
    for (int k = 1; k < 5; ++k) {
      float2 za2 = *reinterpret_cast<const float2*>(&za[2 * k]);
      float2 zb2 = *reinterpret_cast<const float2*>(&zb[2 * k]);
      float2 zc2 = *reinterpret_cast<const float2*>(&zc[2 * k]);
      va += 2.f * (za2.x * tc[k - 1] - za2.y * tsn[k - 1]);
      vb += 2.f * (zb2.x * tc[k - 1] - zb2.y * tsn[k - 1]);
      vc += 2.f * (zc2.x * tc[k - 1] - zc2.y * tsn[k - 1]);
    }
    rva[i] = fmaxf(va * scale, 0.f);
    rvb[i] = fmaxf(vb * scale, 0.f);
    rvc[i] = fmaxf(vc * scale, 0.f);
  }
  long cs = (long)n * n * 64;
  long ob = (long)b * 9 * cs + (long)rem * 64 + t;
  __half* ud = Ud + lv.u_off[lev];
  __half* us = Us + lv.u_off[lev];
#pragma unroll
  for (int o = 0; o < 9; ++o) {
    float du = a_lob[o] + b_lob[o];
    float usv = c_lob[o];
#pragma unroll
    for (int i = 0; i < 9; ++i) {
      du += a_low[o * 9 + i] * rva[i] + b_low[o * 9 + i] * rvb[i];
      usv += c_low[o * 9 + i] * rvc[i];
    }
    ud[ob + o * cs] = __float2half(du);
    us[ob + o * cs] = __float2half(usv);
  }
}

// ---------------- single-pos recon step helper ----------------
__device__ inline void step1pos(const float* __restrict__ in, float* __restrict__ outp,
                                const __half* __restrict__ us, const __half* __restrict__ ud,
                                long chs, const float* __restrict__ rc, int t) {
  float cat[18];
#pragma unroll
  for (int i = 0; i < 9; ++i) cat[i] = in[i * 64 + t] + __half2float(us[chs * i + t]);
#pragma unroll
  for (int i = 0; i < 9; ++i) cat[9 + i] = __half2float(ud[chs * i + t]);
#pragma unroll
  for (int o = 0; o < 9; ++o) {
    float s = 0.f;
#pragma unroll
    for (int i = 0; i < 18; ++i) s += cat[i] * rc[i * 9 + o];
    outp[o * 64 + t] = s;
  }
}

// ---------------- fully fused reconstruction: t0 + all 6 levels ----------------
__global__ __launch_bounds__(256) void k_recon_fused(
    const __half* __restrict__ s5, const float* __restrict__ t0w,
    const float* __restrict__ t0b, const __half* __restrict__ Ud,
    const __half* __restrict__ Us, const float* __restrict__ rcee,
    const float* __restrict__ rceo, const float* __restrict__ roe_,
    const float* __restrict__ roo_, float* __restrict__ out, Levels lv) {
  __shared__ float A[576];
  __shared__ float Bq[576];
  __shared__ float mid[4 * 580];
  __shared__ float big[16 * 580];
  int tid = threadIdx.x;
  int b = blockIdx.x >> 6;
  int T = blockIdx.x & 63;
  int tx = T >> 3, ty = T & 7;
  const float* rcw[4] = {rcee, rceo, roe_, roo_};

  if (tid < 64) {
    int t = tid;
    float v[9];
#pragma unroll
    for (int i = 0; i < 9; ++i) v[i] = __half2float(s5[((long)b * 9 + i) * 64 + t]);
#pragma unroll
    for (int o = 0; o < 9; ++o) {
      float s = t0b[o];
#pragma unroll
      for (int i = 0; i < 9; ++i) s += t0w[o * 9 + i] * v[i];
      A[o * 64 + t] = s;
    }
  }
  __syncthreads();
  if (tid < 64) {
    int t = tid;
    int sel = ((tx >> 2) & 1) * 2 + ((ty >> 2) & 1);
    long base = lv.u_off[5] + (long)b * 9 * 64;
    step1pos(A, Bq, Us + base, Ud + base, 64, rcw[sel], t);
  }
  __syncthreads();
  if (tid < 64) {
    int t = tid;
    int ip = (tx >> 2) * 2 + (ty >> 2);
    int sel = ((tx >> 1) & 1) * 2 + ((ty >> 1) & 1);
    long base = lv.u_off[4] + ((long)b * 9 * 4 + ip) * 64;
    step1pos(Bq, A, Us + base, Ud + base, 4 * 64, rcw[sel], t);
  }
  __syncthreads();
  if (tid < 64) {
    int t = tid;
    int ip = (tx >> 1) * 4 + (ty >> 1);
    int sel = (tx & 1) * 2 + (ty & 1);
    long base = lv.u_off[3] + ((long)b * 9 * 16 + ip) * 64;
    step1pos(A, Bq, Us + base, Ud + base, 16 * 64, rcw[sel], t);
  }
  __syncthreads();
  {
    int q = tid >> 6, t = tid & 63;
    int ip = tx * 8 + ty;
    long base = lv.u_off[2] + ((long)b * 9 * 64 + ip) * 64;
    step1pos(Bq, &mid[q * 580], Us + base, Ud + base, 64 * 64, rcw[q], t);
  }
  __syncthreads();
  {
    int pos16 = tid >> 4, tq = tid & 15;
    int ox = pos16 >> 2, oy = pos16 & 3;
    int q = (ox >> 1) * 2 + (oy >> 1);
    int gx = 2 * tx + (ox >> 1), gy = 2 * ty + (oy >> 1);
    int ip = gx * 16 + gy;
    long base = lv.u_off[1] + ((long)b * 9 * 256 + ip) * 64 + tq * 4;
    const float* rc = rcw[(ox & 1) * 2 + (oy & 1)];
    float cat[18][4];
#pragma unroll
    for (int i = 0; i < 9; ++i) {
      float4 m4 = *reinterpret_cast<const float4*>(&mid[q * 580 + i * 64 + tq * 4]);
      float4 u4 = ld4g(Us + base + (long)i * 256 * 64);
      cat[i][0] = m4.x + u4.x; cat[i][1] = m4.y + u4.y;
      cat[i][2] = m4.z + u4.z; cat[i][3] = m4.w + u4.w;
      float4 d4 = ld4g(Ud + base + (long)i * 256 * 64);
      cat[9 + i][0] = d4.x; cat[9 + i][1] = d4.y; cat[9 + i][2] = d4.z; cat[9 + i][3] = d4.w;
    }
#pragma unroll
    for (int o = 0; o < 9; ++o) {
      float s0 = 0.f, s1 = 0.f, s2 = 0.f, s3 = 0.f;
#pragma unroll
      for (int i = 0; i < 18; ++i) {
        float w = rc[i * 9 + o];
        s0 += cat[i][0] * w; s1 += cat[i][1] * w; s2 += cat[i][2] * w; s3 += cat[i][3] * w;
      }
      *reinterpret_cast<float4*>(&big[pos16 * 580 + o * 64 + tq * 4]) =
          make_float4(s0, s1, s2, s3);
    }
  }
  __syncthreads();
  {
    int q16 = tid >> 4, tq = tid & 15;
    int ix = q16 >> 2, iy = q16 & 3;
    int gx = 4 * tx + ix, gy = 4 * ty + iy;
    int ip = gx * 32 + gy;
    long base = lv.u_off[0] + ((long)b * 9 * 1024 + ip) * 64 + tq * 4;
    float cat[18][4];
#pragma unroll
    for (int i = 0; i < 9; ++i) {
      float4 m4 = *reinterpret_cast<const float4*>(&big[q16 * 580 + i * 64 + tq * 4]);
      float4 u4 = ld4g(Us + base + (long)i * 1024 * 64);
      cat[i][0] = m4.x + u4.x; cat[i][1] = m4.y + u4.y;
      cat[i][2] = m4.z + u4.z; cat[i][3] = m4.w + u4.w;
      float4 d4 = ld4g(Ud + base + (long)i * 1024 * 64);
      cat[9 + i][0] = d4.x; cat[9 + i][1] = d4.y; cat[9 + i][2] = d4.z; cat[9 + i][3] = d4.w;
    }
#pragma unroll
    for (int rx = 0; rx < 2; ++rx)
#pragma unroll
      for (int ry = 0; ry < 2; ++ry) {
        const float* rc = rcw[rx * 2 + ry];
        int X = 8 * tx + 2 * ix + rx, Y = 8 * ty + 2 * iy + ry;
#pragma unroll
        for (int o = 0; o < 9; ++o) {
          float s0 = 0.f, s1 = 0.f, s2 = 0.f, s3 = 0.f;
#pragma unroll
          for (int i = 0; i < 18; ++i) {
            float w = rc[i * 9 + o];
            s0 += cat[i][0] * w; s1 += cat[i][1] * w; s2 += cat[i][2] * w; s3 += cat[i][3] * w;
          }
          *reinterpret_cast<float4*>(
              &out[((((long)b * 9 + o) * 64 + X) * 64 + Y) * 64 + tq * 4]) =
              make_float4(s0, s1, s2, s3);
        }
      }
  }
}

extern "C" void kernel_launch(void* const* d_in, const int* in_sizes, int n_in, void* d_out,
                              int out_size, void* d_ws, size_t ws_size, hipStream_t stream) {
  (void)in_sizes; (void)n_in; (void)out_size; (void)ws_size;
  const float* x = (const float*)d_in[0];
  const float* aw[4] = {(const float*)d_in[1], (const float*)d_in[2], (const float*)d_in[3],
                        (const float*)d_in[4]};
  const float* a_low = (const float*)d_in[5];
  const float* a_lob = (const float*)d_in[6];
  const float* bw[4] = {(const float*)d_in[7], (const float*)d_in[8], (const float*)d_in[9],
                        (const float*)d_in[10]};
  const float* b_low = (const float*)d_in[11];
  const float* b_lob = (const float*)d_in[12];
  const float* cw[4] = {(const float*)d_in[13], (const float*)d_in[14], (const float*)d_in[15],
                        (const float*)d_in[16]};
  const float* c_low = (const float*)d_in[17];
  const float* c_lob = (const float*)d_in[18];
  const float* t0w = (const float*)d_in[19];
  const float* t0b = (const float*)d_in[20];
  const float* ecs = (const float*)d_in[21];
  const float* ecd = (const float*)d_in[22];
  const float* rcee = (const float*)d_in[23];
  const float* rceo = (const float*)d_in[24];
  const float* rcoe = (const float*)d_in[25];
  const float* rcoo = (const float*)d_in[26];

  Levels lv;
  {
    int zt = 0, zxy = 0, gh = 0;
    static const int uoff[6] = {0, 9437184, 11796480, 12386304, 12533760, 12570624};
    for (int lev = 0; lev < 6; ++lev) {
      int n = 32 >> lev;
      int kn = n < 10 ? n : 10;
      lv.n[lev] = n;
      lv.kn[lev] = kn;
      lv.zt_off[lev] = zt;
      lv.zxy_off[lev] = zxy;
      lv.z6_off[lev] = zt;
      lv.u_off[lev] = uoff[lev];
      lv.gstart[lev] = gh;
      lv.scale[lev] = 1.f / sqrtf((float)(n * n * 64));
      zt += NB * 9 * n * n * 10;
      zxy += NB * 9 * kn * kn * 10;
      gh += (NB * n * n + 3) / 4;
    }
    lv.gstart[6] = gh;
  }

  char* base = (char*)d_ws;
  size_t ob = 0;
  auto allocF = [&](size_t ne) { float* p = (float*)(base + ob); ob += ne * 4; return p; };
  auto allocH = [&](size_t ne) {
    __half* p = (__half*)(base + ob);
    ob += ((ne + 1) & ~(size_t)1) * 2;
    return p;
  };
  float* twt = allocF(640);
  float* twx = allocF(3840);
  float* Zt_d = allocF(1965600);
  float* Zt_s = allocF(1965600);
  float* Zxy_d = allocF(410400);
  float* Zxy_s = allocF(410400);
  __half* s_a = allocH(9437184);
  __half* s_b = allocH(9437184);
  __half* Z6a = allocH(1965600);
  __half* Z6b = allocH(1965600);
  __half* Z6c = allocH(1965600);
  __half* Ud = allocH(12579840);
  __half* Us = allocH(12579840);

  k_init<<<1, 256, 0, stream>>>(twt, twx);

  for (int lev = 0; lev < 6; ++lev) {
    int n = 32 >> lev;
    int nblk = (NB * n * n + 3) / 4;
    __half* s_cur = (lev & 1) ? s_b : s_a;
    float* ztd = Zt_d + lv.zt_off[lev];
    float* zts = Zt_s + lv.zt_off[lev];
    if (lev == 0)
      k_wavdft<float><<<nblk, 256, 0, stream>>>(x, ecd, ecs, s_cur, ztd, zts, twt, n,
                                                lv.scale[lev]);
    else
      k_wavdft<__half><<<nblk, 256, 0, stream>>>((lev & 1) ? s_a : s_b, ecd, ecs, s_cur, ztd,
                                                 zts, twt, n, lv.scale[lev]);
  }

  k_bc_all<<<6 * 288, 256, 0, stream>>>(Zt_d, Zt_s, Zxy_d, Zxy_s, twx, lv);
  WArgs wa;
  for (int j = 0; j < 4; ++j) { wa.w[j] = aw[j]; wa.w[4 + j] = bw[j]; wa.w[8 + j] = cw[j]; }
  k_efmix_all<<<6 * 432, 256, 0, stream>>>(Zxy_d, Zxy_s, Z6a, Z6b, Z6c, wa, twx, lv);
  k_gh3_all<<<lv.gstart[6], 256, 0, stream>>>(Z6a, Z6b, Z6c, a_low, a_lob, b_low, b_lob, c_low,
                                              c_lob, Ud, Us, twt, lv);

  k_recon_fused<<<NB * 64, 256, 0, stream>>>(s_b, t0w, t0b, Ud, Us, rcee, rceo, rcoe, rcoo,
                                             (float*)d_out, lv);
}